// Round 11
// baseline (96.883 us; speedup 1.0000x reference)
//
#include <hip/hip_runtime.h>
#include <hip/hip_bf16.h>

// NT-Xent (SimCLR) fused loss, MI355X gfx950. Round 19: 8-wave free-run.
// r18 post-mortem: unique-writer Pcol stores +17us vs r14 atomics (cold
// write-allocate lines + 64-slot finalize gather beat hot-S atomics) ->
// atomic-contention theory falsified; flush reverted to r14 exactly.
// Remaining untested lever: occupancy. Every valid measurement shows
// ~14% (8 waves/CU = 2/SIMD; grid 512 blocks is the cap, VGPR=128 allows
// 16 waves/CU). r10's null was barrier-lockstep; r16's regression had
// confounds (no A-reuse, 4x flush). This round: 512-thread blocks
// (8 waves, 4x2 quadrants, 32x128 per wave), same (8,64) grid -> 2
// blocks/CU x 8 waves = 16 waves/CU = 4/SIMD, free-run, A-reuse and
// flush structure preserved. LB(512,4) caps VGPR at 128.
//
// ws layout: [S: N f32][pos: N f32][znf: N*D fp8 frag-major]

#define N_TOT 8192
#define BATCH 4096
#define DIM   256                    // fp8 bytes per row
#define NT_TILES 64                  // 8192 / 128
#define LOG2E_T 14.4269504089f       // 10 * log2(e)  (temperature folded)

typedef int   v8i32 __attribute__((ext_vector_type(8)));
typedef float f32x4 __attribute__((ext_vector_type(4)));

// znf layout: for 16-row group G (rows G*16+c, c=0..15), k-half h (0/1),
// quad q (0..3): 512-byte block at ((G*2+h)*4+q)*512. Lane c's 32 bytes
// (row G*16+c, row-bytes [16*(8h+2q), +32)) live contiguously at c*32.

// One wave per row: 64 lanes x float4 -> 4 fp8 bytes/lane, scattered into
// fragment-major znf. Also zeros S and out.
__global__ __launch_bounds__(256) void normalize_kernel(
    const float* __restrict__ z, unsigned char* __restrict__ znf,
    float* __restrict__ S, float* __restrict__ out) {
  const int wave = threadIdx.x >> 6;
  const int lane = threadIdx.x & 63;
  const int row  = blockIdx.x * 4 + wave;
  float4 v = ((const float4*)(z + (size_t)row * DIM))[lane];
  float ss = v.x * v.x + v.y * v.y + v.z * v.z + v.w * v.w;
#pragma unroll
  for (int m = 1; m <= 32; m <<= 1) ss += __shfl_xor(ss, m);
  float inv = 1.0f / sqrtf(ss);
  int p01 = __builtin_amdgcn_cvt_pk_fp8_f32(v.x * inv, v.y * inv, 0, false);
  int p23 = __builtin_amdgcn_cvt_pk_fp8_f32(v.z * inv, v.w * inv, 0, false);
  unsigned int packed =
      ((unsigned int)p01 & 0xffffu) | ((unsigned int)p23 << 16);
  const int G = row >> 4, c = row & 15;
  const int h = lane >> 5, q = (lane >> 3) & 3, lb = (lane >> 2) & 1;
  *(unsigned int*)(znf + (((size_t)(G * 2 + h) * 4 + q) << 9) + c * 32 +
                   lb * 16 + (lane & 3) * 4) = packed;
  if (threadIdx.x < 4) S[blockIdx.x * 4 + threadIdx.x] = 0.0f;
  if (blockIdx.x == 0 && threadIdx.x == 0) out[0] = 0.0f;
}

// Load one (row-group, k-half) fragment (32 B/lane) straight from L2.
__device__ __forceinline__ v8i32 load_frag_g(
    const unsigned char* __restrict__ znf, int G, int h, int quad, int c) {
  const int4* p =
      (const int4*)(znf + (((size_t)(G * 2 + h) * 4 + quad) << 9) + c * 32);
  int4 lo = p[0];
  int4 hi = p[1];
  return (v8i32){lo.x, lo.y, lo.z, lo.w, hi.x, hi.y, hi.z, hi.w};
}

// Tile epilogue: register-only. MODE 0 = plain, 1 = diagonal (mask
// self-sim; caller skips col flush -- symmetric, rows cover), 2 = partner
// (jj==32: emit pos logits, plain stores). 8-wave shape: per wave 32 rows
// (wm stripe, fm in 0..1) x 64 cols (wn half).
template <int MODE>
__device__ __forceinline__ void epilogue_tile(
    const f32x4 (&acc)[2][4], float (&rs)[8], float (&cs)[4],
    float* __restrict__ pos, int rb, int cbt, int wm, int wn, int c,
    int quad) {
#pragma unroll
  for (int fm = 0; fm < 2; ++fm) {
#pragma unroll
    for (int r = 0; r < 4; ++r) {
      const int grow = rb * 128 + wm * 32 + fm * 16 + quad * 4 + r;
#pragma unroll
      for (int fn = 0; fn < 4; ++fn) {
        const int gcol = cbt * 128 + wn * 64 + fn * 16 + c;
        // exp(acc*10) == exp2(acc * 10*log2(e)); raw v_exp_f32, no libcall
        float e = __builtin_amdgcn_exp2f(acc[fm][fn][r] * LOG2E_T);
        if (MODE == 1 && gcol == grow) e = 0.f;   // exclude self-similarity
        if (MODE == 2 && ((gcol ^ grow) == BATCH)) {
          const float logit = acc[fm][fn][r] * 10.0f;
          pos[grow] = logit;                       // unique writer/elem
          pos[gcol] = logit;                       // sim symmetric
        }
        rs[fm * 4 + r] += e;
        cs[fn] += e;
      }
    }
  }
}

__global__ __launch_bounds__(512, 4) void simclr_tile_kernel(
    const unsigned char* __restrict__ znf, float* __restrict__ S,
    float* __restrict__ pos) {
  const int g = blockIdx.x;                    // j-group 0..7
  const int rb = blockIdx.y;                   // row band 0..63 (A, fixed)
  const int tid = threadIdx.x;
  const int wave = tid >> 6, lane = tid & 63;
  const int wm = wave >> 1, wn = wave & 1;     // 4x2 quadrants: 32x64/wave
  const int c = lane & 15, quad = lane >> 4;   // MFMA lane coords

  const int ntile = (g == 0 && rb < 32) ? 5 : 4;  // g0 also does j=32

  // A-fragments -> registers once per block, straight from L2.
  // Row-group of (rb, wm, f): G = rb*8 + wm*2 + f.
  v8i32 af[2][2];
#pragma unroll
  for (int f = 0; f < 2; ++f)
#pragma unroll
    for (int h = 0; h < 2; ++h)
      af[f][h] = load_frag_g(znf, rb * 8 + wm * 2 + f, h, quad, c);

  // Per-row exp-sum partials, accumulated across ALL tiles of this block.
  float rs[8];
#pragma unroll
  for (int i = 0; i < 8; ++i) rs[i] = 0.f;

  for (int t = 0; t < ntile; ++t) {
    const int jj = (t == 4) ? 32 : (g * 4 + t);
    const int cbt = (rb + jj) & 63;

    // All 16 B-fragment loads issued up front (independent, L2-resident).
    v8i32 bf[4][2];
#pragma unroll
    for (int f = 0; f < 4; ++f)
#pragma unroll
      for (int h = 0; h < 2; ++h)
        bf[f][h] = load_frag_g(znf, cbt * 8 + wn * 4 + f, h, quad, c);

    f32x4 acc[2][4];
#pragma unroll
    for (int i = 0; i < 2; ++i)
#pragma unroll
      for (int k = 0; k < 4; ++k) acc[i][k] = (f32x4){0.f, 0.f, 0.f, 0.f};

#pragma unroll
    for (int h = 0; h < 2; ++h)
#pragma unroll
      for (int fm = 0; fm < 2; ++fm)
#pragma unroll
        for (int fn = 0; fn < 4; ++fn)
          acc[fm][fn] = __builtin_amdgcn_mfma_scale_f32_16x16x128_f8f6f4(
              af[fm][h], bf[fn][h], acc[fm][fn],
              0, 0,                 // cbsz = fp8(A), blgp = fp8(B)
              0, 0x7f,              // opsel_a, scale_a = E8M0 1.0
              0, 0x7f);             // opsel_b, scale_b = E8M0 1.0

    // Register epilogue, specialized per tile kind (uniform branch).
    float cs[4] = {0.f, 0.f, 0.f, 0.f};
    if (g == 0 && t == 0)
      epilogue_tile<1>(acc, rs, cs, pos, rb, cbt, wm, wn, c, quad);
    else if (t == 4)
      epilogue_tile<2>(acc, rs, cs, pos, rb, cbt, wm, wn, c, quad);
    else
      epilogue_tile<0>(acc, rs, cs, pos, rb, cbt, wm, wn, c, quad);

    // Column sums (transpose contribution); diag tile skipped (symmetric;
    // row sums cover it). 4 wm-waves contribute per column via atomics.
    if (!(g == 0 && t == 0)) {
#pragma unroll
      for (int fn = 0; fn < 4; ++fn) {
        float v = cs[fn];
        v += __shfl_xor(v, 16);
        v += __shfl_xor(v, 32);
        if (quad == 0)
          atomicAdd(&S[cbt * 128 + wn * 64 + fn * 16 + c], v);
      }
    }
  }

  // Row sums: shuffle-reduce + one atomic per row.
#pragma unroll
  for (int fm = 0; fm < 2; ++fm) {
#pragma unroll
    for (int r = 0; r < 4; ++r) {
      float s = rs[fm * 4 + r];
      s += __shfl_xor(s, 1);
      s += __shfl_xor(s, 2);
      s += __shfl_xor(s, 4);
      s += __shfl_xor(s, 8);
      if (c == 0) {
        const int grow = rb * 128 + wm * 32 + fm * 16 + quad * 4 + r;
        atomicAdd(&S[grow], s);
      }
    }
  }
}

// loss = mean(log(S_i) - pos_i); 16 blocks, atomic accumulate into out.
__global__ __launch_bounds__(512) void finalize_kernel(
    const float* __restrict__ S, const float* __restrict__ pos,
    float* __restrict__ out) {
  const int i = blockIdx.x * 512 + threadIdx.x;
  float a = __logf(S[i]) - pos[i];
#pragma unroll
  for (int m = 1; m <= 32; m <<= 1) a += __shfl_xor(a, m);
  __shared__ float red[8];
  if ((threadIdx.x & 63) == 0) red[threadIdx.x >> 6] = a;
  __syncthreads();
  if (threadIdx.x < 8) {
    float v = red[threadIdx.x];
    v += __shfl_xor(v, 1);
    v += __shfl_xor(v, 2);
    v += __shfl_xor(v, 4);
    if (threadIdx.x == 0) atomicAdd(out, v * (1.0f / (float)N_TOT));
  }
}

extern "C" void kernel_launch(void* const* d_in, const int* in_sizes, int n_in,
                              void* d_out, int out_size, void* d_ws,
                              size_t ws_size, hipStream_t stream) {
  const float* z = (const float*)d_in[0];
  float* out = (float*)d_out;
  char* ws = (char*)d_ws;
  float* S = (float*)ws;                                   // N floats
  float* pos = (float*)(ws + N_TOT * sizeof(float));       // N floats
  unsigned char* znf =
      (unsigned char*)(ws + 2 * N_TOT * sizeof(float));    // N*D fp8

  normalize_kernel<<<N_TOT / 4, 256, 0, stream>>>(z, znf, S, out);
  dim3 grid(8, NT_TILES);
  simclr_tile_kernel<<<grid, 512, 0, stream>>>(znf, S, pos);
  finalize_kernel<<<N_TOT / 512, 512, 0, stream>>>(S, pos, out);
}

// Round 12
// 82.130 us; speedup vs baseline: 1.1796x; 1.1796x over previous
//
#include <hip/hip_runtime.h>
#include <hip/hip_bf16.h>

// NT-Xent (SimCLR) fused loss, MI355X gfx950. Round 20: r19 with the
// launch-bounds fix. r19 post-mortem: LB(512,4) was interpreted as 4
// BLOCKS/CU (CUDA semantics) -> 32 waves/CU -> 64-VGPR cap (counter
// confirmed VGPR_Count=64) -> per-tile scratch spill (symmetric FETCH
// 44.5MB / WRITE 47.9MB blob, the r12 signature). The 8-wave occupancy
// test never ran. This round: LB(512,2) -- under either semantics the
// cap is >=128 VGPR (2 blocks/CU x 8 waves = 16 waves/CU = 4/SIMD),
// fitting the ~90-reg working set spill-free. Everything else identical.
//
// ws layout: [S: N f32][pos: N f32][znf: N*D fp8 frag-major]

#define N_TOT 8192
#define BATCH 4096
#define DIM   256                    // fp8 bytes per row
#define NT_TILES 64                  // 8192 / 128
#define LOG2E_T 14.4269504089f       // 10 * log2(e)  (temperature folded)

typedef int   v8i32 __attribute__((ext_vector_type(8)));
typedef float f32x4 __attribute__((ext_vector_type(4)));

// znf layout: for 16-row group G (rows G*16+c, c=0..15), k-half h (0/1),
// quad q (0..3): 512-byte block at ((G*2+h)*4+q)*512. Lane c's 32 bytes
// (row G*16+c, row-bytes [16*(8h+2q), +32)) live contiguously at c*32.

// One wave per row: 64 lanes x float4 -> 4 fp8 bytes/lane, scattered into
// fragment-major znf. Also zeros S and out.
__global__ __launch_bounds__(256) void normalize_kernel(
    const float* __restrict__ z, unsigned char* __restrict__ znf,
    float* __restrict__ S, float* __restrict__ out) {
  const int wave = threadIdx.x >> 6;
  const int lane = threadIdx.x & 63;
  const int row  = blockIdx.x * 4 + wave;
  float4 v = ((const float4*)(z + (size_t)row * DIM))[lane];
  float ss = v.x * v.x + v.y * v.y + v.z * v.z + v.w * v.w;
#pragma unroll
  for (int m = 1; m <= 32; m <<= 1) ss += __shfl_xor(ss, m);
  float inv = 1.0f / sqrtf(ss);
  int p01 = __builtin_amdgcn_cvt_pk_fp8_f32(v.x * inv, v.y * inv, 0, false);
  int p23 = __builtin_amdgcn_cvt_pk_fp8_f32(v.z * inv, v.w * inv, 0, false);
  unsigned int packed =
      ((unsigned int)p01 & 0xffffu) | ((unsigned int)p23 << 16);
  const int G = row >> 4, c = row & 15;
  const int h = lane >> 5, q = (lane >> 3) & 3, lb = (lane >> 2) & 1;
  *(unsigned int*)(znf + (((size_t)(G * 2 + h) * 4 + q) << 9) + c * 32 +
                   lb * 16 + (lane & 3) * 4) = packed;
  if (threadIdx.x < 4) S[blockIdx.x * 4 + threadIdx.x] = 0.0f;
  if (blockIdx.x == 0 && threadIdx.x == 0) out[0] = 0.0f;
}

// Load one (row-group, k-half) fragment (32 B/lane) straight from L2.
__device__ __forceinline__ v8i32 load_frag_g(
    const unsigned char* __restrict__ znf, int G, int h, int quad, int c) {
  const int4* p =
      (const int4*)(znf + (((size_t)(G * 2 + h) * 4 + quad) << 9) + c * 32);
  int4 lo = p[0];
  int4 hi = p[1];
  return (v8i32){lo.x, lo.y, lo.z, lo.w, hi.x, hi.y, hi.z, hi.w};
}

// Tile epilogue: register-only. MODE 0 = plain, 1 = diagonal (mask
// self-sim; caller skips col flush -- symmetric, rows cover), 2 = partner
// (jj==32: emit pos logits, plain stores). 8-wave shape: per wave 32 rows
// (wm stripe, fm in 0..1) x 64 cols (wn half).
template <int MODE>
__device__ __forceinline__ void epilogue_tile(
    const f32x4 (&acc)[2][4], float (&rs)[8], float (&cs)[4],
    float* __restrict__ pos, int rb, int cbt, int wm, int wn, int c,
    int quad) {
#pragma unroll
  for (int fm = 0; fm < 2; ++fm) {
#pragma unroll
    for (int r = 0; r < 4; ++r) {
      const int grow = rb * 128 + wm * 32 + fm * 16 + quad * 4 + r;
#pragma unroll
      for (int fn = 0; fn < 4; ++fn) {
        const int gcol = cbt * 128 + wn * 64 + fn * 16 + c;
        // exp(acc*10) == exp2(acc * 10*log2(e)); raw v_exp_f32, no libcall
        float e = __builtin_amdgcn_exp2f(acc[fm][fn][r] * LOG2E_T);
        if (MODE == 1 && gcol == grow) e = 0.f;   // exclude self-similarity
        if (MODE == 2 && ((gcol ^ grow) == BATCH)) {
          const float logit = acc[fm][fn][r] * 10.0f;
          pos[grow] = logit;                       // unique writer/elem
          pos[gcol] = logit;                       // sim symmetric
        }
        rs[fm * 4 + r] += e;
        cs[fn] += e;
      }
    }
  }
}

__global__ __launch_bounds__(512, 2) void simclr_tile_kernel(
    const unsigned char* __restrict__ znf, float* __restrict__ S,
    float* __restrict__ pos) {
  const int g = blockIdx.x;                    // j-group 0..7
  const int rb = blockIdx.y;                   // row band 0..63 (A, fixed)
  const int tid = threadIdx.x;
  const int wave = tid >> 6, lane = tid & 63;
  const int wm = wave >> 1, wn = wave & 1;     // 4x2 quadrants: 32x64/wave
  const int c = lane & 15, quad = lane >> 4;   // MFMA lane coords

  const int ntile = (g == 0 && rb < 32) ? 5 : 4;  // g0 also does j=32

  // A-fragments -> registers once per block, straight from L2.
  // Row-group of (rb, wm, f): G = rb*8 + wm*2 + f.
  v8i32 af[2][2];
#pragma unroll
  for (int f = 0; f < 2; ++f)
#pragma unroll
    for (int h = 0; h < 2; ++h)
      af[f][h] = load_frag_g(znf, rb * 8 + wm * 2 + f, h, quad, c);

  // Per-row exp-sum partials, accumulated across ALL tiles of this block.
  float rs[8];
#pragma unroll
  for (int i = 0; i < 8; ++i) rs[i] = 0.f;

  for (int t = 0; t < ntile; ++t) {
    const int jj = (t == 4) ? 32 : (g * 4 + t);
    const int cbt = (rb + jj) & 63;

    // All 16 B-fragment loads issued up front (independent, L2-resident).
    v8i32 bf[4][2];
#pragma unroll
    for (int f = 0; f < 4; ++f)
#pragma unroll
      for (int h = 0; h < 2; ++h)
        bf[f][h] = load_frag_g(znf, cbt * 8 + wn * 4 + f, h, quad, c);

    f32x4 acc[2][4];
#pragma unroll
    for (int i = 0; i < 2; ++i)
#pragma unroll
      for (int k = 0; k < 4; ++k) acc[i][k] = (f32x4){0.f, 0.f, 0.f, 0.f};

#pragma unroll
    for (int h = 0; h < 2; ++h)
#pragma unroll
      for (int fm = 0; fm < 2; ++fm)
#pragma unroll
        for (int fn = 0; fn < 4; ++fn)
          acc[fm][fn] = __builtin_amdgcn_mfma_scale_f32_16x16x128_f8f6f4(
              af[fm][h], bf[fn][h], acc[fm][fn],
              0, 0,                 // cbsz = fp8(A), blgp = fp8(B)
              0, 0x7f,              // opsel_a, scale_a = E8M0 1.0
              0, 0x7f);             // opsel_b, scale_b = E8M0 1.0

    // Register epilogue, specialized per tile kind (uniform branch).
    float cs[4] = {0.f, 0.f, 0.f, 0.f};
    if (g == 0 && t == 0)
      epilogue_tile<1>(acc, rs, cs, pos, rb, cbt, wm, wn, c, quad);
    else if (t == 4)
      epilogue_tile<2>(acc, rs, cs, pos, rb, cbt, wm, wn, c, quad);
    else
      epilogue_tile<0>(acc, rs, cs, pos, rb, cbt, wm, wn, c, quad);

    // Column sums (transpose contribution); diag tile skipped (symmetric;
    // row sums cover it). 4 wm-waves contribute per column via atomics.
    if (!(g == 0 && t == 0)) {
#pragma unroll
      for (int fn = 0; fn < 4; ++fn) {
        float v = cs[fn];
        v += __shfl_xor(v, 16);
        v += __shfl_xor(v, 32);
        if (quad == 0)
          atomicAdd(&S[cbt * 128 + wn * 64 + fn * 16 + c], v);
      }
    }
  }

  // Row sums: shuffle-reduce + one atomic per row.
#pragma unroll
  for (int fm = 0; fm < 2; ++fm) {
#pragma unroll
    for (int r = 0; r < 4; ++r) {
      float s = rs[fm * 4 + r];
      s += __shfl_xor(s, 1);
      s += __shfl_xor(s, 2);
      s += __shfl_xor(s, 4);
      s += __shfl_xor(s, 8);
      if (c == 0) {
        const int grow = rb * 128 + wm * 32 + fm * 16 + quad * 4 + r;
        atomicAdd(&S[grow], s);
      }
    }
  }
}

// loss = mean(log(S_i) - pos_i); 16 blocks, atomic accumulate into out.
__global__ __launch_bounds__(512) void finalize_kernel(
    const float* __restrict__ S, const float* __restrict__ pos,
    float* __restrict__ out) {
  const int i = blockIdx.x * 512 + threadIdx.x;
  float a = __logf(S[i]) - pos[i];
#pragma unroll
  for (int m = 1; m <= 32; m <<= 1) a += __shfl_xor(a, m);
  __shared__ float red[8];
  if ((threadIdx.x & 63) == 0) red[threadIdx.x >> 6] = a;
  __syncthreads();
  if (threadIdx.x < 8) {
    float v = red[threadIdx.x];
    v += __shfl_xor(v, 1);
    v += __shfl_xor(v, 2);
    v += __shfl_xor(v, 4);
    if (threadIdx.x == 0) atomicAdd(out, v * (1.0f / (float)N_TOT));
  }
}

extern "C" void kernel_launch(void* const* d_in, const int* in_sizes, int n_in,
                              void* d_out, int out_size, void* d_ws,
                              size_t ws_size, hipStream_t stream) {
  const float* z = (const float*)d_in[0];
  float* out = (float*)d_out;
  char* ws = (char*)d_ws;
  float* S = (float*)ws;                                   // N floats
  float* pos = (float*)(ws + N_TOT * sizeof(float));       // N floats
  unsigned char* znf =
      (unsigned char*)(ws + 2 * N_TOT * sizeof(float));    // N*D fp8

  normalize_kernel<<<N_TOT / 4, 256, 0, stream>>>(z, znf, S, out);
  dim3 grid(8, NT_TILES);
  simclr_tile_kernel<<<grid, 512, 0, stream>>>(znf, S, pos);
  finalize_kernel<<<N_TOT / 512, 512, 0, stream>>>(S, pos, out);
}

// Round 13
// 78.854 us; speedup vs baseline: 1.2286x; 1.0415x over previous
//
#include <hip/hip_runtime.h>
#include <hip/hip_bf16.h>

// NT-Xent (SimCLR) fused loss, MI355X gfx950. Round 21: LDS-merged column
// flush. r20: occupancy null in free-run too (falsified). Fresh r17
// counter read: WRITE 9.2MB / FETCH 9.8MB on a 64KB output -> the ~663K
// device-scope atomicAdds execute as MEMORY-SIDE line RMWs (cross-XCD
// coherence forces L2 bypass); hot S lines take ~150 serialized RMWs.
// Invisible to MfmaUtil/VALUBusy -- matches "all pipes idle". Fix: column
// partials accumulate in LDS (ds_add_f32, fire-and-forget, merges wm
// duplicates, no per-tile barrier), then ONE coalesced global-atomic
// burst per block after a single block-end barrier (~10 64-lane instrs,
// ~40 lines vs ~80 instrs / ~65 lines scattered). Base = r14 exactly.
//
// ws layout: [S: N f32][pos: N f32][znf: N*D fp8 frag-major]

#define N_TOT 8192
#define BATCH 4096
#define DIM   256                    // fp8 bytes per row
#define NT_TILES 64                  // 8192 / 128
#define LOG2E_T 14.4269504089f       // 10 * log2(e)  (temperature folded)

typedef int   v8i32 __attribute__((ext_vector_type(8)));
typedef float f32x4 __attribute__((ext_vector_type(4)));

// znf layout: for 16-row group G (rows G*16+c, c=0..15), k-half h (0/1),
// quad q (0..3): 512-byte block at ((G*2+h)*4+q)*512. Lane c's 32 bytes
// (row G*16+c, row-bytes [16*(8h+2q), +32)) live contiguously at c*32.

// One wave per row: 64 lanes x float4 -> 4 fp8 bytes/lane, scattered into
// fragment-major znf. Also zeros S and out.
__global__ __launch_bounds__(256) void normalize_kernel(
    const float* __restrict__ z, unsigned char* __restrict__ znf,
    float* __restrict__ S, float* __restrict__ out) {
  const int wave = threadIdx.x >> 6;
  const int lane = threadIdx.x & 63;
  const int row  = blockIdx.x * 4 + wave;
  float4 v = ((const float4*)(z + (size_t)row * DIM))[lane];
  float ss = v.x * v.x + v.y * v.y + v.z * v.z + v.w * v.w;
#pragma unroll
  for (int m = 1; m <= 32; m <<= 1) ss += __shfl_xor(ss, m);
  float inv = 1.0f / sqrtf(ss);
  int p01 = __builtin_amdgcn_cvt_pk_fp8_f32(v.x * inv, v.y * inv, 0, false);
  int p23 = __builtin_amdgcn_cvt_pk_fp8_f32(v.z * inv, v.w * inv, 0, false);
  unsigned int packed =
      ((unsigned int)p01 & 0xffffu) | ((unsigned int)p23 << 16);
  const int G = row >> 4, c = row & 15;
  const int h = lane >> 5, q = (lane >> 3) & 3, lb = (lane >> 2) & 1;
  *(unsigned int*)(znf + (((size_t)(G * 2 + h) * 4 + q) << 9) + c * 32 +
                   lb * 16 + (lane & 3) * 4) = packed;
  if (threadIdx.x < 4) S[blockIdx.x * 4 + threadIdx.x] = 0.0f;
  if (blockIdx.x == 0 && threadIdx.x == 0) out[0] = 0.0f;
}

// Load one (row-group, k-half) fragment (32 B/lane) straight from L2.
__device__ __forceinline__ v8i32 load_frag_g(
    const unsigned char* __restrict__ znf, int G, int h, int quad, int c) {
  const int4* p =
      (const int4*)(znf + (((size_t)(G * 2 + h) * 4 + quad) << 9) + c * 32);
  int4 lo = p[0];
  int4 hi = p[1];
  return (v8i32){lo.x, lo.y, lo.z, lo.w, hi.x, hi.y, hi.z, hi.w};
}

// Tile epilogue: register-only. MODE 0 = plain, 1 = diagonal (mask
// self-sim; caller skips col flush -- symmetric, rows cover), 2 = partner
// (jj==32: emit pos logits, plain stores).
template <int MODE>
__device__ __forceinline__ void epilogue_tile(
    const f32x4 (&acc)[4][4], float (&rs)[16], float (&cs)[4],
    float* __restrict__ pos, int rb, int cbt, int wm, int wn, int c,
    int quad) {
#pragma unroll
  for (int fm = 0; fm < 4; ++fm) {
#pragma unroll
    for (int r = 0; r < 4; ++r) {
      const int grow = rb * 128 + wm * 64 + fm * 16 + quad * 4 + r;
#pragma unroll
      for (int fn = 0; fn < 4; ++fn) {
        const int gcol = cbt * 128 + wn * 64 + fn * 16 + c;
        // exp(acc*10) == exp2(acc * 10*log2(e)); raw v_exp_f32, no libcall
        float e = __builtin_amdgcn_exp2f(acc[fm][fn][r] * LOG2E_T);
        if (MODE == 1 && gcol == grow) e = 0.f;   // exclude self-similarity
        if (MODE == 2 && ((gcol ^ grow) == BATCH)) {
          const float logit = acc[fm][fn][r] * 10.0f;
          pos[grow] = logit;                       // unique writer/elem
          pos[gcol] = logit;                       // sim symmetric
        }
        rs[fm * 4 + r] += e;
        cs[fn] += e;
      }
    }
  }
}

__global__ __launch_bounds__(256, 2) void simclr_tile_kernel(
    const unsigned char* __restrict__ znf, float* __restrict__ S,
    float* __restrict__ pos) {
  const int g = blockIdx.x;                    // j-group 0..7
  const int rb = blockIdx.y;                   // row band 0..63 (A, fixed)
  const int tid = threadIdx.x;
  const int wave = tid >> 6, lane = tid & 63;
  const int wm = wave >> 1, wn = wave & 1;     // wave quadrant (2x2)
  const int c = lane & 15, quad = lane >> 4;   // MFMA lane coords

  const int ntile = (g == 0 && rb < 32) ? 5 : 4;  // g0 also does j=32

  // Per-tile column partials, accumulated in LDS (cheap ds_add_f32; wm
  // duplicates merge here instead of at HBM-side atomics).
  __shared__ float colpart[5][128];             // 2.5 KB
  for (int i = tid; i < 5 * 128; i += 256) ((float*)colpart)[i] = 0.f;

  // A-fragments -> registers once per block, straight from L2.
  v8i32 af[4][2];
#pragma unroll
  for (int f = 0; f < 4; ++f)
#pragma unroll
    for (int h = 0; h < 2; ++h)
      af[f][h] = load_frag_g(znf, rb * 8 + wm * 4 + f, h, quad, c);

  // Per-row exp-sum partials, accumulated across ALL tiles of this block.
  float rs[16];
#pragma unroll
  for (int i = 0; i < 16; ++i) rs[i] = 0.f;

  __syncthreads();   // colpart zeroed before any ds_add

  for (int t = 0; t < ntile; ++t) {
    const int jj = (t == 4) ? 32 : (g * 4 + t);
    const int cbt = (rb + jj) & 63;

    // All 16 B-fragment loads issued up front (independent, L2-resident).
    v8i32 bf[4][2];
#pragma unroll
    for (int f = 0; f < 4; ++f)
#pragma unroll
      for (int h = 0; h < 2; ++h)
        bf[f][h] = load_frag_g(znf, cbt * 8 + wn * 4 + f, h, quad, c);

    f32x4 acc[4][4];
#pragma unroll
    for (int i = 0; i < 4; ++i)
#pragma unroll
      for (int k = 0; k < 4; ++k) acc[i][k] = (f32x4){0.f, 0.f, 0.f, 0.f};

#pragma unroll
    for (int h = 0; h < 2; ++h)
#pragma unroll
      for (int fm = 0; fm < 4; ++fm)
#pragma unroll
        for (int fn = 0; fn < 4; ++fn)
          acc[fm][fn] = __builtin_amdgcn_mfma_scale_f32_16x16x128_f8f6f4(
              af[fm][h], bf[fn][h], acc[fm][fn],
              0, 0,                 // cbsz = fp8(A), blgp = fp8(B)
              0, 0x7f,              // opsel_a, scale_a = E8M0 1.0
              0, 0x7f);             // opsel_b, scale_b = E8M0 1.0

    // Register epilogue, specialized per tile kind (uniform branch).
    float cs[4] = {0.f, 0.f, 0.f, 0.f};
    if (g == 0 && t == 0)
      epilogue_tile<1>(acc, rs, cs, pos, rb, cbt, wm, wn, c, quad);
    else if (t == 4)
      epilogue_tile<2>(acc, rs, cs, pos, rb, cbt, wm, wn, c, quad);
    else
      epilogue_tile<0>(acc, rs, cs, pos, rb, cbt, wm, wn, c, quad);

    // Column partials -> LDS atomics (fire-and-forget, lgkm pipe; no
    // global RMW inside the loop). Diag tile skipped (symmetric).
    if (!(g == 0 && t == 0)) {
#pragma unroll
      for (int fn = 0; fn < 4; ++fn) {
        float v = cs[fn];
        v += __shfl_xor(v, 16);
        v += __shfl_xor(v, 32);
        if (quad == 0) atomicAdd(&colpart[t][wn * 64 + fn * 16 + c], v);
      }
    }
  }

  // Row sums: shuffle-reduce + one global atomic per row (unchanged).
#pragma unroll
  for (int fm = 0; fm < 4; ++fm) {
#pragma unroll
    for (int r = 0; r < 4; ++r) {
      float s = rs[fm * 4 + r];
      s += __shfl_xor(s, 1);
      s += __shfl_xor(s, 2);
      s += __shfl_xor(s, 4);
      s += __shfl_xor(s, 8);
      if (c == 0) {
        const int grow = rb * 128 + wm * 64 + fm * 16 + quad * 4 + r;
        atomicAdd(&S[grow], s);
      }
    }
  }

  __syncthreads();   // all ds_adds visible

  // Column flush: one coalesced burst per block. 640 values -> ~10
  // 64-lane atomic instrs, consecutive addresses within each tile band.
  for (int idx = tid; idx < ntile * 128; idx += 256) {
    const int t = idx >> 7, col = idx & 127;
    if (!(g == 0 && t == 0)) {
      const int jj = (t == 4) ? 32 : (g * 4 + t);
      const int cbt = (rb + jj) & 63;
      atomicAdd(&S[cbt * 128 + col], colpart[t][col]);
    }
  }
}

// loss = mean(log(S_i) - pos_i); single block (cheap, ~2us).
__global__ __launch_bounds__(1024) void finalize_kernel(
    const float* __restrict__ S, const float* __restrict__ pos,
    float* __restrict__ out) {
  const int tid = threadIdx.x;
  float a = 0.f;
  for (int i = tid; i < N_TOT; i += 1024) a += __logf(S[i]) - pos[i];
#pragma unroll
  for (int m = 1; m <= 32; m <<= 1) a += __shfl_xor(a, m);
  __shared__ float red[16];
  if ((tid & 63) == 0) red[tid >> 6] = a;
  __syncthreads();
  if (tid < 16) {
    float v = red[tid];
    v += __shfl_xor(v, 1);
    v += __shfl_xor(v, 2);
    v += __shfl_xor(v, 4);
    v += __shfl_xor(v, 8);
    if (tid == 0) out[0] = v * (1.0f / (float)N_TOT);
  }
}

extern "C" void kernel_launch(void* const* d_in, const int* in_sizes, int n_in,
                              void* d_out, int out_size, void* d_ws,
                              size_t ws_size, hipStream_t stream) {
  const float* z = (const float*)d_in[0];
  float* out = (float*)d_out;
  char* ws = (char*)d_ws;
  float* S = (float*)ws;                                   // N floats
  float* pos = (float*)(ws + N_TOT * sizeof(float));       // N floats
  unsigned char* znf =
      (unsigned char*)(ws + 2 * N_TOT * sizeof(float));    // N*D fp8

  normalize_kernel<<<N_TOT / 4, 256, 0, stream>>>(z, znf, S, out);
  dim3 grid(8, NT_TILES);
  simclr_tile_kernel<<<grid, 256, 0, stream>>>(znf, S, pos);
  finalize_kernel<<<1, 1024, 0, stream>>>(S, pos, out);
}